// Round 8
// baseline (120.608 us; speedup 1.0000x reference)
//
#include <hip/hip_runtime.h>
#include <math.h>

// B=2, C=1, H=W=2048, RADIUS=1, RK=3; J center plane is zeroed in setup.
namespace {
constexpr int H = 2048;
constexpr int W = 2048;
constexpr int NPIX = H * W;            // 2^22
constexpr int B = 2;
constexpr float DECf = 0.95f;
constexpr float OMDf = 1.0f - 0.95f;
}

using f4 = __attribute__((ext_vector_type(4))) float;

// R8 = R7 with the swizzle-width bug fixed (R7 crashed: <<11 decoded a
// 16384-unit space against an 8192 grid -> h up to 3839 -> OOB).
// Structure: R3's exact thread shape (f4 loads, 4 px/thread, 256 thr,
// VGPR ~52, occ ~39% -- measured 4.05 TB/s) + J-read-once via the CACHE:
// unit u = (row, half)*2 + batch; XCD-chunk swizzle (8192 = 8 x 1024,
// bijective) puts the batch pair of the same position (and neighboring
// rows) on the SAME XCD at the same time, so the second batch's J and
// rand_drop reads hit L2/L3 -- J fetched from HBM once -- without R5's
// thread-fusion VGPR/wave-count cost.
// Numerics: decision path (tap-sum in tap order, delta_e, exp, compare) in
// f64 (passed 6x); EMA observables in f32 (passed R3-R6, absmax 0.0078).
__global__ __launch_bounds__(256, 4) void ising_step_kernel(
    const float* __restrict__ x,      // (B, 2, H, W): s then b
    const float* __restrict__ obvs,   // (B, 4, H, W): e, e2, c, m
    const float* __restrict__ Jm,     // (1, 9, N)
    const float* __restrict__ rs,     // (B, 1, H, W)
    const float* __restrict__ rd,     // (1, 1, H, W)
    float* __restrict__ out)          // state (B,2,N) ++ obvs_out (B,4,N)
{
  const int bid = blockIdx.x;
  const int u   = ((bid & 7) << 10) | (bid >> 3);  // 8 XCDs x 1024 units
  const int bi  = u & 1;                           // batch pair adjacent
  const int pu  = u >> 1;                          // (row, half) in [0,4096)
  const int h   = pu >> 1;                         // [0,2048)
  const int w0  = ((pu & 1) << 10) | (threadIdx.x << 2);
  const int n0  = (h << 11) | w0;

  const float* sbase = x + (size_t)bi * 2 * NPIX;
  const int hm = (h - 1) & (H - 1);
  const int hp = (h + 1) & (H - 1);
  const float* rowm = sbase + (size_t)hm * W;
  const float* rowc = sbase + (size_t)h  * W;
  const float* rowp = sbase + (size_t)hp * W;
  const int wl = (w0 - 1) & (W - 1);
  const int wr = (w0 + 4) & (W - 1);

  // ---- all loads issued before compute ----
  const f4 vm = *(const f4*)(rowm + w0);
  const f4 vc = *(const f4*)(rowc + w0);
  const f4 vp = *(const f4*)(rowp + w0);
  const float lm = rowm[wl], rm = rowm[wr];
  const float lc = rowc[wl], rc = rowc[wr];
  const float lp = rowp[wl], rp = rowp[wr];

  f4 jv[8];
  #pragma unroll
  for (int k = 0; k < 8; ++k) {
    const int kk = (k < 4) ? k : (k + 1);   // skip zeroed center plane
    jv[k] = *(const f4*)(Jm + (size_t)kk * NPIX + n0);
  }

  const f4 bv  = *(const f4*)(sbase + (size_t)NPIX + n0);
  const float* ob = obvs + (size_t)bi * 4 * NPIX + n0;
  const f4 ev  = *(const f4*)(ob);
  const f4 e2v = *(const f4*)(ob + (size_t)NPIX);
  const f4 cv  = *(const f4*)(ob + 2 * (size_t)NPIX);
  const f4 mv  = *(const f4*)(ob + 3 * (size_t)NPIX);
  const f4 rv  = *(const f4*)(rs + (size_t)bi * NPIX + n0);
  const f4 dv  = *(const f4*)(rd + n0);

  const float am[6] = {lm, vm.x, vm.y, vm.z, vm.w, rm};
  const float ac[6] = {lc, vc.x, vc.y, vc.z, vc.w, rc};
  const float ap[6] = {lp, vp.x, vp.y, vp.z, vp.w, rp};

  const float bq[4]  = {bv.x, bv.y, bv.z, bv.w};
  const float eq[4]  = {ev.x, ev.y, ev.z, ev.w};
  const float e2q[4] = {e2v.x, e2v.y, e2v.z, e2v.w};
  const float cq[4]  = {cv.x, cv.y, cv.z, cv.w};
  const float mq[4]  = {mv.x, mv.y, mv.z, mv.w};
  const float rsq[4] = {rv.x, rv.y, rv.z, rv.w};
  const float rdq[4] = {dv.x, dv.y, dv.z, dv.w};

  float so[4], eo[4], e2o[4], co[4], mo[4];
  #pragma unroll
  for (int t = 0; t < 4; ++t) {
    // decision-critical path in f64, reference tap order
    const double sum =
        (double)jv[0][t] * am[t]     + (double)jv[1][t] * am[t + 1] +
        (double)jv[2][t] * am[t + 2] + (double)jv[3][t] * ac[t]     +
        (double)jv[4][t] * ac[t + 2] + (double)jv[5][t] * ap[t]     +
        (double)jv[6][t] * ap[t + 1] + (double)jv[7][t] * ap[t + 2];
    const float sf  = ac[t + 1];
    const double s  = (double)sf;
    const double de = 2.0 * s * sum;
    const double p  = (de <= 0.0) ? 1.0 : exp(-de * (double)bq[t]);
    const bool acc  = ((double)rsq[t] < p) && (rdq[t] > 0.5f);
    // observables in f32
    const float E   = (float)(-s * sum);
    const float bf  = bq[t];
    const float en  = DECf * eq[t]  + OMDf * E;
    const float e2n = DECf * e2q[t] + OMDf * E * E;
    const float cn  = DECf * cq[t]  + OMDf * (e2n - en * en) * bf * bf;
    const float mn  = DECf * mq[t]  + OMDf * sf;
    so[t]  = acc ? -sf : sf;
    eo[t]  = en;
    e2o[t] = e2n;
    co[t]  = cn;
    mo[t]  = mn;
  }

  float* st = out + (size_t)bi * 2 * NPIX;
  float* oo = out + (size_t)B * 2 * NPIX + (size_t)bi * 4 * NPIX;
  *(f4*)(st + n0)                     = (f4){so[0], so[1], so[2], so[3]};
  *(f4*)(st + (size_t)NPIX + n0)      = bv;
  *(f4*)(oo + n0)                     = (f4){eo[0], eo[1], eo[2], eo[3]};
  *(f4*)(oo + (size_t)NPIX + n0)      = (f4){e2o[0], e2o[1], e2o[2], e2o[3]};
  *(f4*)(oo + 2 * (size_t)NPIX + n0)  = (f4){co[0], co[1], co[2], co[3]};
  *(f4*)(oo + 3 * (size_t)NPIX + n0)  = (f4){mo[0], mo[1], mo[2], mo[3]};
}

extern "C" void kernel_launch(void* const* d_in, const int* in_sizes, int n_in,
                              void* d_out, int out_size, void* d_ws, size_t ws_size,
                              hipStream_t stream) {
  const float* x    = (const float*)d_in[0];
  const float* obvs = (const float*)d_in[1];
  const float* Jm   = (const float*)d_in[2];
  const float* rs   = (const float*)d_in[3];
  const float* rd   = (const float*)d_in[4];
  float* out = (float*)d_out;

  constexpr int grid = B * H * 2;   // 8192 (batch, row, half) units
  ising_step_kernel<<<grid, 256, 0, stream>>>(x, obvs, Jm, rs, rd, out);
}

// Round 9
// 116.427 us; speedup vs baseline: 1.0359x; 1.0359x over previous
//
#include <hip/hip_runtime.h>
#include <math.h>

// B=2, C=1, H=W=2048, RADIUS=1, RK=3; J center plane is zeroed in setup.
namespace {
constexpr int H = 2048;
constexpr int W = 2048;
constexpr int NPIX = H * W;            // 2^22
constexpr int B = 2;
constexpr float DECf = 0.95f;
constexpr float OMDf = 1.0f - 0.95f;
}

using f4 = __attribute__((ext_vector_type(4))) float;

// R9: attack the VMEM ISSUE-RATE roofline (R3/R5/R6/R8 all pinned at
// ~115-123 us with ~30 VMEM instr per 4 px ~= 0.85 instr/cy/CU -- time was
// invariant to HBM bytes, occupancy, and load width; the invariant was the
// VMEM instruction count). Cut 30 -> 24 by replacing the 6 scalar halo
// loads with an LDS edge-exchange on the (idle) lgkm pipe:
//   - thread t holds elements [4t..4t+3] of each row in registers;
//   - it publishes .x (= right-neighbor value of thread t-1) to slot 2t and
//     .w (= left-neighbor value of thread t+1) to slot 2t+3 (one mergeable
//     ds_write2_b32 per row; 2-way bank aliasing = free);
//   - block-edge dwords (6 total) loaded by lanes 0-5 of wave 0 (1 VMEM
//     instr, amortized);
//   - after one barrier, thread t reads L=slot 2t+1, R=slot 2t+2
//     (one ds_read2_b32 per row).
// Slot map: L(t)=2t+1, R(t)=2t+2; halo L(0)=1, R(255)=512. Values are
// bit-identical to R8's scalar-load version.
// Grid/swizzle = R8: 8192 (batch,row,half) units, batch pair adjacent on
// the same XCD (J/rd fetched from HBM once, sibling hits L2/L3); bijective.
// Numerics: decision path (tap-sum in tap order, delta_e, exp, compare) in
// f64 (passed 7x); EMA observables in f32 (passed R3-R8, absmax 0.0078).
__global__ __launch_bounds__(256, 4) void ising_step_kernel(
    const float* __restrict__ x,      // (B, 2, H, W): s then b
    const float* __restrict__ obvs,   // (B, 4, H, W): e, e2, c, m
    const float* __restrict__ Jm,     // (1, 9, N)
    const float* __restrict__ rs,     // (B, 1, H, W)
    const float* __restrict__ rd,     // (1, 1, H, W)
    float* __restrict__ out)          // state (B,2,N) ++ obvs_out (B,4,N)
{
  __shared__ float lr[3][520];

  const int bid = blockIdx.x;
  const int u   = ((bid & 7) << 10) | (bid >> 3);  // 8 XCDs x 1024 units
  const int bi  = u & 1;                           // batch pair adjacent
  const int pu  = u >> 1;                          // (row, half) in [0,4096)
  const int h   = pu >> 1;                         // [0,2048)
  const int t   = threadIdx.x;
  const int w0b = (pu & 1) << 10;                  // block's first pixel col
  const int w0  = w0b | (t << 2);
  const int n0  = (h << 11) | w0;

  const float* sbase = x + (size_t)bi * 2 * NPIX;
  const int hm = (h - 1) & (H - 1);
  const int hp = (h + 1) & (H - 1);
  const float* rowm = sbase + (size_t)hm * W;
  const float* rowc = sbase + (size_t)h  * W;
  const float* rowp = sbase + (size_t)hp * W;

  // ---- row loads first (LDS writes depend only on these) ----
  const f4 vm = *(const f4*)(rowm + w0);
  const f4 vc = *(const f4*)(rowc + w0);
  const f4 vp = *(const f4*)(rowp + w0);

  // ---- remaining loads issued while LDS exchange proceeds ----
  f4 jv[8];
  #pragma unroll
  for (int k = 0; k < 8; ++k) {
    const int kk = (k < 4) ? k : (k + 1);   // skip zeroed center plane
    jv[k] = *(const f4*)(Jm + (size_t)kk * NPIX + n0);
  }
  const f4 bv  = *(const f4*)(sbase + (size_t)NPIX + n0);
  const float* ob = obvs + (size_t)bi * 4 * NPIX + n0;
  const f4 ev  = *(const f4*)(ob);
  const f4 e2v = *(const f4*)(ob + (size_t)NPIX);
  const f4 cv  = *(const f4*)(ob + 2 * (size_t)NPIX);
  const f4 mv  = *(const f4*)(ob + 3 * (size_t)NPIX);
  const f4 rv  = *(const f4*)(rs + (size_t)bi * NPIX + n0);
  const f4 dv  = *(const f4*)(rd + n0);

  // ---- LDS edge exchange ----
  lr[0][2 * t] = vm.x;  lr[0][2 * t + 3] = vm.w;
  lr[1][2 * t] = vc.x;  lr[1][2 * t + 3] = vc.w;
  lr[2][2 * t] = vp.x;  lr[2][2 * t + 3] = vp.w;
  if (t < 6) {
    const int r    = t >> 1;
    const int side = t & 1;
    const float* rowr = (r == 0) ? rowm : ((r == 1) ? rowc : rowp);
    const int wsrc = side ? ((w0b + 1024) & (W - 1)) : ((w0b - 1) & (W - 1));
    lr[r][side ? 512 : 1] = rowr[wsrc];
  }
  __syncthreads();
  const float Lm = lr[0][2 * t + 1], Rm = lr[0][2 * t + 2];
  const float Lc = lr[1][2 * t + 1], Rc = lr[1][2 * t + 2];
  const float Lp = lr[2][2 * t + 1], Rp = lr[2][2 * t + 2];

  const float am[6] = {Lm, vm.x, vm.y, vm.z, vm.w, Rm};
  const float ac[6] = {Lc, vc.x, vc.y, vc.z, vc.w, Rc};
  const float ap[6] = {Lp, vp.x, vp.y, vp.z, vp.w, Rp};

  const float bq[4]  = {bv.x, bv.y, bv.z, bv.w};
  const float eq[4]  = {ev.x, ev.y, ev.z, ev.w};
  const float e2q[4] = {e2v.x, e2v.y, e2v.z, e2v.w};
  const float cq[4]  = {cv.x, cv.y, cv.z, cv.w};
  const float mq[4]  = {mv.x, mv.y, mv.z, mv.w};
  const float rsq[4] = {rv.x, rv.y, rv.z, rv.w};
  const float rdq[4] = {dv.x, dv.y, dv.z, dv.w};

  float so[4], eo[4], e2o[4], co[4], mo[4];
  #pragma unroll
  for (int tt = 0; tt < 4; ++tt) {
    // decision-critical path in f64, reference tap order
    const double sum =
        (double)jv[0][tt] * am[tt]     + (double)jv[1][tt] * am[tt + 1] +
        (double)jv[2][tt] * am[tt + 2] + (double)jv[3][tt] * ac[tt]     +
        (double)jv[4][tt] * ac[tt + 2] + (double)jv[5][tt] * ap[tt]     +
        (double)jv[6][tt] * ap[tt + 1] + (double)jv[7][tt] * ap[tt + 2];
    const float sf  = ac[tt + 1];
    const double s  = (double)sf;
    const double de = 2.0 * s * sum;
    const double p  = (de <= 0.0) ? 1.0 : exp(-de * (double)bq[tt]);
    const bool acc  = ((double)rsq[tt] < p) && (rdq[tt] > 0.5f);
    // observables in f32
    const float E   = (float)(-s * sum);
    const float bf  = bq[tt];
    const float en  = DECf * eq[tt]  + OMDf * E;
    const float e2n = DECf * e2q[tt] + OMDf * E * E;
    const float cn  = DECf * cq[tt]  + OMDf * (e2n - en * en) * bf * bf;
    const float mn  = DECf * mq[tt]  + OMDf * sf;
    so[tt]  = acc ? -sf : sf;
    eo[tt]  = en;
    e2o[tt] = e2n;
    co[tt]  = cn;
    mo[tt]  = mn;
  }

  float* st = out + (size_t)bi * 2 * NPIX;
  float* oo = out + (size_t)B * 2 * NPIX + (size_t)bi * 4 * NPIX;
  *(f4*)(st + n0)                     = (f4){so[0], so[1], so[2], so[3]};
  *(f4*)(st + (size_t)NPIX + n0)      = bv;
  *(f4*)(oo + n0)                     = (f4){eo[0], eo[1], eo[2], eo[3]};
  *(f4*)(oo + (size_t)NPIX + n0)      = (f4){e2o[0], e2o[1], e2o[2], e2o[3]};
  *(f4*)(oo + 2 * (size_t)NPIX + n0)  = (f4){co[0], co[1], co[2], co[3]};
  *(f4*)(oo + 3 * (size_t)NPIX + n0)  = (f4){mo[0], mo[1], mo[2], mo[3]};
}

extern "C" void kernel_launch(void* const* d_in, const int* in_sizes, int n_in,
                              void* d_out, int out_size, void* d_ws, size_t ws_size,
                              hipStream_t stream) {
  const float* x    = (const float*)d_in[0];
  const float* obvs = (const float*)d_in[1];
  const float* Jm   = (const float*)d_in[2];
  const float* rs   = (const float*)d_in[3];
  const float* rd   = (const float*)d_in[4];
  float* out = (float*)d_out;

  constexpr int grid = B * H * 2;   // 8192 (batch, row, half) units
  ising_step_kernel<<<grid, 256, 0, stream>>>(x, obvs, Jm, rs, rd, out);
}

// Round 10
// 110.306 us; speedup vs baseline: 1.0934x; 1.0555x over previous
//
#include <hip/hip_runtime.h>
#include <math.h>

// B=2, C=1, H=W=2048, RADIUS=1, RK=3; J center plane is zeroed in setup.
namespace {
constexpr int H = 2048;
constexpr int W = 2048;
constexpr int NPIX = H * W;            // 2^22
constexpr int B = 2;
constexpr float DECf = 0.95f;
constexpr float OMDf = 1.0f - 0.95f;
}

using f4 = __attribute__((ext_vector_type(4))) float;

// R10 = R9 + NONTEMPORAL STORES ONLY (single-variable A/B vs R9).
// Evidence: time pinned 115-123 us across R3-R9, invariant to HBM bytes
// (189-498 MB), occupancy (17.5-40%), load width, VMEM count, MLP. Last
// surviving theory: L3 (Infinity Cache) service bound -- ~197 MB/replay of
// reads are L3 hits + 197 MB of write inserts evict resident inputs.
// Outputs are never re-read -> nt stores keep them from claiming L3,
// improving input retention (FETCH must drop if theory holds) and cutting
// L3 insert traffic. Loads stay cached (R2 showed NT loads kill reuse).
// Everything else identical to R9: LDS halo exchange (VMEM 24/thread),
// batch-pair-adjacent XCD swizzle (J fetched once), f4 loads, 4 px/thread.
// Numerics: decision path f64 (passed 8x); EMA f32 (absmax 0.0078 stable).
__global__ __launch_bounds__(256, 4) void ising_step_kernel(
    const float* __restrict__ x,      // (B, 2, H, W): s then b
    const float* __restrict__ obvs,   // (B, 4, H, W): e, e2, c, m
    const float* __restrict__ Jm,     // (1, 9, N)
    const float* __restrict__ rs,     // (B, 1, H, W)
    const float* __restrict__ rd,     // (1, 1, H, W)
    float* __restrict__ out)          // state (B,2,N) ++ obvs_out (B,4,N)
{
  __shared__ float lr[3][520];

  const int bid = blockIdx.x;
  const int u   = ((bid & 7) << 10) | (bid >> 3);  // 8 XCDs x 1024 units
  const int bi  = u & 1;                           // batch pair adjacent
  const int pu  = u >> 1;                          // (row, half) in [0,4096)
  const int h   = pu >> 1;                         // [0,2048)
  const int t   = threadIdx.x;
  const int w0b = (pu & 1) << 10;                  // block's first pixel col
  const int w0  = w0b | (t << 2);
  const int n0  = (h << 11) | w0;

  const float* sbase = x + (size_t)bi * 2 * NPIX;
  const int hm = (h - 1) & (H - 1);
  const int hp = (h + 1) & (H - 1);
  const float* rowm = sbase + (size_t)hm * W;
  const float* rowc = sbase + (size_t)h  * W;
  const float* rowp = sbase + (size_t)hp * W;

  // ---- row loads first (LDS writes depend only on these) ----
  const f4 vm = *(const f4*)(rowm + w0);
  const f4 vc = *(const f4*)(rowc + w0);
  const f4 vp = *(const f4*)(rowp + w0);

  // ---- remaining loads issued while LDS exchange proceeds ----
  f4 jv[8];
  #pragma unroll
  for (int k = 0; k < 8; ++k) {
    const int kk = (k < 4) ? k : (k + 1);   // skip zeroed center plane
    jv[k] = *(const f4*)(Jm + (size_t)kk * NPIX + n0);
  }
  const f4 bv  = *(const f4*)(sbase + (size_t)NPIX + n0);
  const float* ob = obvs + (size_t)bi * 4 * NPIX + n0;
  const f4 ev  = *(const f4*)(ob);
  const f4 e2v = *(const f4*)(ob + (size_t)NPIX);
  const f4 cv  = *(const f4*)(ob + 2 * (size_t)NPIX);
  const f4 mv  = *(const f4*)(ob + 3 * (size_t)NPIX);
  const f4 rv  = *(const f4*)(rs + (size_t)bi * NPIX + n0);
  const f4 dv  = *(const f4*)(rd + n0);

  // ---- LDS edge exchange ----
  lr[0][2 * t] = vm.x;  lr[0][2 * t + 3] = vm.w;
  lr[1][2 * t] = vc.x;  lr[1][2 * t + 3] = vc.w;
  lr[2][2 * t] = vp.x;  lr[2][2 * t + 3] = vp.w;
  if (t < 6) {
    const int r    = t >> 1;
    const int side = t & 1;
    const float* rowr = (r == 0) ? rowm : ((r == 1) ? rowc : rowp);
    const int wsrc = side ? ((w0b + 1024) & (W - 1)) : ((w0b - 1) & (W - 1));
    lr[r][side ? 512 : 1] = rowr[wsrc];
  }
  __syncthreads();
  const float Lm = lr[0][2 * t + 1], Rm = lr[0][2 * t + 2];
  const float Lc = lr[1][2 * t + 1], Rc = lr[1][2 * t + 2];
  const float Lp = lr[2][2 * t + 1], Rp = lr[2][2 * t + 2];

  const float am[6] = {Lm, vm.x, vm.y, vm.z, vm.w, Rm};
  const float ac[6] = {Lc, vc.x, vc.y, vc.z, vc.w, Rc};
  const float ap[6] = {Lp, vp.x, vp.y, vp.z, vp.w, Rp};

  const float bq[4]  = {bv.x, bv.y, bv.z, bv.w};
  const float eq[4]  = {ev.x, ev.y, ev.z, ev.w};
  const float e2q[4] = {e2v.x, e2v.y, e2v.z, e2v.w};
  const float cq[4]  = {cv.x, cv.y, cv.z, cv.w};
  const float mq[4]  = {mv.x, mv.y, mv.z, mv.w};
  const float rsq[4] = {rv.x, rv.y, rv.z, rv.w};
  const float rdq[4] = {dv.x, dv.y, dv.z, dv.w};

  float so[4], eo[4], e2o[4], co[4], mo[4];
  #pragma unroll
  for (int tt = 0; tt < 4; ++tt) {
    // decision-critical path in f64, reference tap order
    const double sum =
        (double)jv[0][tt] * am[tt]     + (double)jv[1][tt] * am[tt + 1] +
        (double)jv[2][tt] * am[tt + 2] + (double)jv[3][tt] * ac[tt]     +
        (double)jv[4][tt] * ac[tt + 2] + (double)jv[5][tt] * ap[tt]     +
        (double)jv[6][tt] * ap[tt + 1] + (double)jv[7][tt] * ap[tt + 2];
    const float sf  = ac[tt + 1];
    const double s  = (double)sf;
    const double de = 2.0 * s * sum;
    const double p  = (de <= 0.0) ? 1.0 : exp(-de * (double)bq[tt]);
    const bool acc  = ((double)rsq[tt] < p) && (rdq[tt] > 0.5f);
    // observables in f32
    const float E   = (float)(-s * sum);
    const float bf  = bq[tt];
    const float en  = DECf * eq[tt]  + OMDf * E;
    const float e2n = DECf * e2q[tt] + OMDf * E * E;
    const float cn  = DECf * cq[tt]  + OMDf * (e2n - en * en) * bf * bf;
    const float mn  = DECf * mq[tt]  + OMDf * sf;
    so[tt]  = acc ? -sf : sf;
    eo[tt]  = en;
    e2o[tt] = e2n;
    co[tt]  = cn;
    mo[tt]  = mn;
  }

  // ---- outputs: nontemporal (never re-read; don't claim L2/L3) ----
  float* st = out + (size_t)bi * 2 * NPIX;
  float* oo = out + (size_t)B * 2 * NPIX + (size_t)bi * 4 * NPIX;
  __builtin_nontemporal_store((f4){so[0], so[1], so[2], so[3]}, (f4*)(st + n0));
  __builtin_nontemporal_store(bv, (f4*)(st + (size_t)NPIX + n0));
  __builtin_nontemporal_store((f4){eo[0], eo[1], eo[2], eo[3]}, (f4*)(oo + n0));
  __builtin_nontemporal_store((f4){e2o[0], e2o[1], e2o[2], e2o[3]},
                              (f4*)(oo + (size_t)NPIX + n0));
  __builtin_nontemporal_store((f4){co[0], co[1], co[2], co[3]},
                              (f4*)(oo + 2 * (size_t)NPIX + n0));
  __builtin_nontemporal_store((f4){mo[0], mo[1], mo[2], mo[3]},
                              (f4*)(oo + 3 * (size_t)NPIX + n0));
}

extern "C" void kernel_launch(void* const* d_in, const int* in_sizes, int n_in,
                              void* d_out, int out_size, void* d_ws, size_t ws_size,
                              hipStream_t stream) {
  const float* x    = (const float*)d_in[0];
  const float* obvs = (const float*)d_in[1];
  const float* Jm   = (const float*)d_in[2];
  const float* rs   = (const float*)d_in[3];
  const float* rd   = (const float*)d_in[4];
  float* out = (float*)d_out;

  constexpr int grid = B * H * 2;   // 8192 (batch, row, half) units
  ising_step_kernel<<<grid, 256, 0, stream>>>(x, obvs, Jm, rs, rd, out);
}